// Round 6
// baseline (65404.755 us; speedup 1.0000x reference)
//
#include <hip/hip_runtime.h>

#define SEQ 32768
#define ISZ 256
#define HSZ 512
#define OSZ 256
#define GWG 8            // workgroups (64 rows each)
#define RTHREADS 512     // 8 waves per WG
#define RINGD 4          // tagged partial-exchange ring depth

typedef unsigned long long u64;

// ---------------------------------------------------------------------------
// Generic tiled GEMM:  C[M,N] = A[M,K] @ W[N,K]^T + bias[N]
// ---------------------------------------------------------------------------
__global__ __launch_bounds__(256) void gemm_bt_bias(
    const float* __restrict__ A, const float* __restrict__ W,
    const float* __restrict__ bias, float* __restrict__ C,
    int M, int N, int K)
{
  __shared__ float As[32][68];
  __shared__ float Bs[32][68];
  const int tx = threadIdx.x;
  const int tn = tx & 15, tm = tx >> 4;
  const int m0 = blockIdx.x * 64, n0 = blockIdx.y * 64;
  const int kl = tx & 31;
  const int rl = tx >> 5;
  float acc[4][4] = {};

  for (int kt = 0; kt < K; kt += 32) {
#pragma unroll
    for (int i = 0; i < 8; ++i) {
      int m = rl + i * 8;
      As[kl][m] = A[(size_t)(m0 + m) * K + kt + kl];
      Bs[kl][m] = W[(size_t)(n0 + m) * K + kt + kl];
    }
    __syncthreads();
#pragma unroll
    for (int k = 0; k < 32; ++k) {
      float a[4], b[4];
#pragma unroll
      for (int i = 0; i < 4; ++i) a[i] = As[k][tm * 4 + i];
#pragma unroll
      for (int j = 0; j < 4; ++j) b[j] = Bs[k][tn * 4 + j];
#pragma unroll
      for (int i = 0; i < 4; ++i)
#pragma unroll
        for (int j = 0; j < 4; ++j)
          acc[i][j] = fmaf(a[i], b[j], acc[i][j]);
    }
    __syncthreads();
  }
#pragma unroll
  for (int i = 0; i < 4; ++i) {
    int m = m0 + tm * 4 + i;
#pragma unroll
    for (int j = 0; j < 4; ++j) {
      int n = n0 + tn * 4 + j;
      C[(size_t)m * N + n] = acc[i][j] + bias[n];
    }
  }
}

// ---------------------------------------------------------------------------
// Persistent recurrence, ROUND-6: barrier-free wave-to-wave partial exchange.
//
// h_{s} = tanh(P[s-1] + Wh h_{s-1}).  Decomposition: wave (g,w) of WG g holds
// Wh[rows 64g..64g+64) x [cols 64w..64w+64) (one row-chunk x col-chunk tile,
// 64 floats/lane).  Per step s it:
//   1. polls ring slots [s-1][w][q] (q=0..7): the 8 partials of h chunk w,
//      each an 8-byte {tag=s-1, value} written atomically (never torn);
//   2. sums them + P[s-1] + tanh  -> h_s chunk w  (computed redundantly by
//      the 8 WGs — 60 cy, vs round-4's barrier + wave-0-only reduce);
//   3. dot: partial for rows of g over chunk w (readlane broadcast of h);
//   4. publishes {tag=s, partial} to ring slot [s][g][w] (one dwordx2 sc1
//      store, fire-and-forget — the tag IS the ready signal, no fences).
// NO __syncthreads, NO LDS, NO sentinel resets.  Ring depth 4 is safe: a
// wave publishing tag s implies (2-hop dependency cone over the dense
// coupling) every wave has consumed tag >= s-3, so overwriting tag s-4 in
// slot s&3 can race with nothing.  Correctness is placement-independent
// (L3/agent scope) — round 5's XCD-clustered sc0 design hung; never again.
// ---------------------------------------------------------------------------
__global__ __launch_bounds__(RTHREADS, 2) void rnn_recur(
    const float* __restrict__ P,     // [SEQ][HSZ]  (Wx@x_t + bh)
    const float* __restrict__ Wh,    // [HSZ][HSZ]
    float* __restrict__ h_hist,      // [SEQ+1][HSZ]; rows 1.. written by WG0
    u64* __restrict__ ring)          // [RINGD][8 rowchunk][8 colchunk][64]
{
  const int g = blockIdx.x;
  const int tid = threadIdx.x;
  const int w = tid >> 6;          // wave index = my h chunk / weight col-chunk
  const int l = tid & 63;          // lane = row within WG slice / h element
  const int g64 = g << 6, w64 = w << 6;

  // Weights Wh[g64+l][w64 .. w64+64) — 16 x float4 (live in unified VGPR/AGPR
  // file; VALU reads AGPR operands directly on gfx950).
  float4 wreg[16];
  {
    const float4* wsrc = (const float4*)(Wh + (size_t)(g64 + l) * HSZ + w64);
#pragma unroll
    for (int j4 = 0; j4 < 16; ++j4) {
      float4 v = wsrc[j4];
      asm volatile("" : "+v"(v.x), "+v"(v.y), "+v"(v.z), "+v"(v.w));
      wreg[j4] = v;
    }
  }

  // Fixed per-lane ring addresses (phase d adds d*4096 u64s).
  u64* const pub0 = ring + (size_t)g * (8 * 64) + (size_t)w * 64 + l;
  const u64* const con0 = ring + (size_t)w * (8 * 64) + l;

  // s=0: h_0 = 0, so every partial is 0.0f with tag 0 -> packed value 0.
  __hip_atomic_store(pub0, 0ull, __ATOMIC_RELAXED, __HIP_MEMORY_SCOPE_AGENT);

  // P prefetch registers: pvE holds P[even idx], pvO holds P[odd idx].
  float pvE = P[(size_t)0 * HSZ + w64 + l];
  float pvO = P[(size_t)1 * HSZ + w64 + l];

#define RL(v, ln) __uint_as_float(__builtin_amdgcn_readlane(__float_as_uint(v), (ln)))

#define STEP(s, pv) {                                                          \
    const unsigned tgt = (unsigned)((s) - 1);                                  \
    const u64* cp = con0 + (size_t)(((s) - 1) & 3) * 4096;                     \
    u64 q0, q1, q2, q3, q4, q5, q6, q7;                                        \
    for (;;) {                                                                 \
      q0 = __hip_atomic_load(cp + 0 * 64, __ATOMIC_RELAXED, __HIP_MEMORY_SCOPE_AGENT); \
      q1 = __hip_atomic_load(cp + 1 * 64, __ATOMIC_RELAXED, __HIP_MEMORY_SCOPE_AGENT); \
      q2 = __hip_atomic_load(cp + 2 * 64, __ATOMIC_RELAXED, __HIP_MEMORY_SCOPE_AGENT); \
      q3 = __hip_atomic_load(cp + 3 * 64, __ATOMIC_RELAXED, __HIP_MEMORY_SCOPE_AGENT); \
      q4 = __hip_atomic_load(cp + 4 * 64, __ATOMIC_RELAXED, __HIP_MEMORY_SCOPE_AGENT); \
      q5 = __hip_atomic_load(cp + 5 * 64, __ATOMIC_RELAXED, __HIP_MEMORY_SCOPE_AGENT); \
      q6 = __hip_atomic_load(cp + 6 * 64, __ATOMIC_RELAXED, __HIP_MEMORY_SCOPE_AGENT); \
      q7 = __hip_atomic_load(cp + 7 * 64, __ATOMIC_RELAXED, __HIP_MEMORY_SCOPE_AGENT); \
      int ok = ((unsigned)(q0 >> 32) == tgt) & ((unsigned)(q1 >> 32) == tgt)   \
             & ((unsigned)(q2 >> 32) == tgt) & ((unsigned)(q3 >> 32) == tgt)   \
             & ((unsigned)(q4 >> 32) == tgt) & ((unsigned)(q5 >> 32) == tgt)   \
             & ((unsigned)(q6 >> 32) == tgt) & ((unsigned)(q7 >> 32) == tgt);  \
      if (__all(ok)) break;                                                    \
    }                                                                          \
    float sum = __uint_as_float((unsigned)q0);                                 \
    sum += __uint_as_float((unsigned)q1);                                      \
    sum += __uint_as_float((unsigned)q2);                                      \
    sum += __uint_as_float((unsigned)q3);                                      \
    sum += __uint_as_float((unsigned)q4);                                      \
    sum += __uint_as_float((unsigned)q5);                                      \
    sum += __uint_as_float((unsigned)q6);                                      \
    sum += __uint_as_float((unsigned)q7);                                      \
    float xv = sum + (pv);                                                     \
    (pv) = P[(size_t)(((s) + 1 < SEQ) ? (s) + 1 : SEQ - 1) * HSZ + w64 + l];   \
    xv = fminf(fmaxf(xv, -15.f), 15.f);                                        \
    float e = __expf(2.f * xv);                                                \
    float hn = 1.f - 2.f / (e + 1.f);                                          \
    if (g == 0) h_hist[(size_t)(s) * HSZ + w64 + l] = hn;                      \
    float a0 = 0.f, a1 = 0.f, a2 = 0.f, a3 = 0.f;                              \
    _Pragma("unroll")                                                          \
    for (int j4 = 0; j4 < 16; ++j4) {                                          \
      float4 wv = wreg[j4];                                                    \
      a0 = fmaf(wv.x, RL(hn, 4 * j4 + 0), a0);                                 \
      a1 = fmaf(wv.y, RL(hn, 4 * j4 + 1), a1);                                 \
      a2 = fmaf(wv.z, RL(hn, 4 * j4 + 2), a2);                                 \
      a3 = fmaf(wv.w, RL(hn, 4 * j4 + 3), a3);                                 \
    }                                                                          \
    float pt = (a0 + a1) + (a2 + a3);                                          \
    u64 pk = ((u64)(unsigned)(s) << 32) | (u64)__float_as_uint(pt);            \
    __hip_atomic_store(pub0 + (size_t)((s) & 3) * 4096, pk,                    \
                       __ATOMIC_RELAXED, __HIP_MEMORY_SCOPE_AGENT);            \
  }

  // s = 1 .. SEQ-1 (publish steps). Unroll-2 keeps pvE/pvO in fixed regs.
  for (int s = 1; s <= SEQ - 2; s += 2) {
    STEP(s, pvE);       // odd s: uses P[s-1] (even), refills P[s+1] (even)
    STEP(s + 1, pvO);   // even s: uses P[s-1] (odd),  refills P[s+1] (odd)
  }
  STEP(SEQ - 1, pvE);   // s = 32767 (odd)

  // Epilogue s = SEQ: consume tag SEQ-1, write h_hist[SEQ]. WG0 only.
  if (g == 0) {
    const unsigned tgt = (unsigned)(SEQ - 1);
    const u64* cp = con0 + (size_t)((SEQ - 1) & 3) * 4096;
    u64 q0, q1, q2, q3, q4, q5, q6, q7;
    for (;;) {
      q0 = __hip_atomic_load(cp + 0 * 64, __ATOMIC_RELAXED, __HIP_MEMORY_SCOPE_AGENT);
      q1 = __hip_atomic_load(cp + 1 * 64, __ATOMIC_RELAXED, __HIP_MEMORY_SCOPE_AGENT);
      q2 = __hip_atomic_load(cp + 2 * 64, __ATOMIC_RELAXED, __HIP_MEMORY_SCOPE_AGENT);
      q3 = __hip_atomic_load(cp + 3 * 64, __ATOMIC_RELAXED, __HIP_MEMORY_SCOPE_AGENT);
      q4 = __hip_atomic_load(cp + 4 * 64, __ATOMIC_RELAXED, __HIP_MEMORY_SCOPE_AGENT);
      q5 = __hip_atomic_load(cp + 5 * 64, __ATOMIC_RELAXED, __HIP_MEMORY_SCOPE_AGENT);
      q6 = __hip_atomic_load(cp + 6 * 64, __ATOMIC_RELAXED, __HIP_MEMORY_SCOPE_AGENT);
      q7 = __hip_atomic_load(cp + 7 * 64, __ATOMIC_RELAXED, __HIP_MEMORY_SCOPE_AGENT);
      int ok = ((unsigned)(q0 >> 32) == tgt) & ((unsigned)(q1 >> 32) == tgt)
             & ((unsigned)(q2 >> 32) == tgt) & ((unsigned)(q3 >> 32) == tgt)
             & ((unsigned)(q4 >> 32) == tgt) & ((unsigned)(q5 >> 32) == tgt)
             & ((unsigned)(q6 >> 32) == tgt) & ((unsigned)(q7 >> 32) == tgt);
      if (__all(ok)) break;
    }
    float sum = __uint_as_float((unsigned)q0);
    sum += __uint_as_float((unsigned)q1);
    sum += __uint_as_float((unsigned)q2);
    sum += __uint_as_float((unsigned)q3);
    sum += __uint_as_float((unsigned)q4);
    sum += __uint_as_float((unsigned)q5);
    sum += __uint_as_float((unsigned)q6);
    sum += __uint_as_float((unsigned)q7);
    float xv = sum + pvO;                      // P[SEQ-1] (odd index)
    xv = fminf(fmaxf(xv, -15.f), 15.f);
    float e = __expf(2.f * xv);
    h_hist[(size_t)SEQ * HSZ + w64 + l] = 1.f - 2.f / (e + 1.f);
  }
#undef RL
#undef STEP
}

// ---------------------------------------------------------------------------
extern "C" void kernel_launch(void* const* d_in, const int* in_sizes, int n_in,
                              void* d_out, int out_size, void* d_ws, size_t ws_size,
                              hipStream_t stream) {
  const float* x  = (const float*)d_in[0];  // [SEQ][ISZ]
  const float* Wx = (const float*)d_in[1];  // [HSZ][ISZ]
  const float* Wh = (const float*)d_in[2];  // [HSZ][HSZ]
  const float* Wy = (const float*)d_in[3];  // [OSZ][HSZ]
  const float* bh = (const float*)d_in[4];  // [HSZ]
  const float* by = (const float*)d_in[5];  // [OSZ]
  float* out = (float*)d_out;               // [SEQ][OSZ]

  float* P      = (float*)d_ws;             // SEQ*HSZ      (64 MB)
  float* h_hist = P + (size_t)SEQ * HSZ;    // (SEQ+1)*HSZ  (64 MB)
  u64*   ring   = (u64*)(h_hist + (size_t)(SEQ + 1) * HSZ); // 128 KB

  // Reset ring tags (0xFFFFFFFF != any step tag). Tiny (128 KB).
  hipMemsetAsync(ring, 0xFF, (size_t)RINGD * 8 * 8 * 64 * sizeof(u64), stream);

  // Phase 1: P = x @ Wx^T + bh
  gemm_bt_bias<<<dim3(SEQ / 64, HSZ / 64), dim3(256), 0, stream>>>(
      x, Wx, bh, P, SEQ, HSZ, ISZ);

  // Phase 2: sequential recurrence (8 persistent co-resident WGs)
  rnn_recur<<<dim3(GWG), dim3(RTHREADS), 0, stream>>>(P, Wh, h_hist, ring);

  // Phase 3: y = h_hist[1..] @ Wy^T + by
  gemm_bt_bias<<<dim3(SEQ / 64, OSZ / 64), dim3(256), 0, stream>>>(
      h_hist + HSZ, Wy, by, out, SEQ, OSZ, HSZ);
}

// Round 7
// 43373.849 us; speedup vs baseline: 1.5079x; 1.5079x over previous
//
#include <hip/hip_runtime.h>

#define SEQ 32768
#define ISZ 256
#define HSZ 512
#define OSZ 256
#define GWG 2            // TWO workgroups (256 rows each) — minimal agents
#define RTHREADS 512     // 8 waves per WG
#define SENT 0x7FAAAAAAu // NaN sentinel: h = tanh(finite) is never NaN

typedef _Float16 half2_t __attribute__((ext_vector_type(2)));

#if defined(__has_builtin)
#if __has_builtin(__builtin_amdgcn_fdot2)
#define HAVE_FDOT2 1
#endif
#endif

__device__ __forceinline__ float dot2f(half2_t a, half2_t b, float c) {
#ifdef HAVE_FDOT2
  return __builtin_amdgcn_fdot2(a, b, c, false);   // v_dot2_f32_f16
#else
  return fmaf((float)a.x, (float)b.x, fmaf((float)a.y, (float)b.y, c));
#endif
}
__device__ __forceinline__ half2_t bch2(unsigned u) {
  return __builtin_bit_cast(half2_t, u);
}

// ---------------------------------------------------------------------------
// Generic tiled GEMM:  C[M,N] = A[M,K] @ W[N,K]^T + bias[N]
// ---------------------------------------------------------------------------
__global__ __launch_bounds__(256) void gemm_bt_bias(
    const float* __restrict__ A, const float* __restrict__ W,
    const float* __restrict__ bias, float* __restrict__ C,
    int M, int N, int K)
{
  __shared__ float As[32][68];
  __shared__ float Bs[32][68];
  const int tx = threadIdx.x;
  const int tn = tx & 15, tm = tx >> 4;
  const int m0 = blockIdx.x * 64, n0 = blockIdx.y * 64;
  const int kl = tx & 31;
  const int rl = tx >> 5;
  float acc[4][4] = {};

  for (int kt = 0; kt < K; kt += 32) {
#pragma unroll
    for (int i = 0; i < 8; ++i) {
      int m = rl + i * 8;
      As[kl][m] = A[(size_t)(m0 + m) * K + kt + kl];
      Bs[kl][m] = W[(size_t)(n0 + m) * K + kt + kl];
    }
    __syncthreads();
#pragma unroll
    for (int k = 0; k < 32; ++k) {
      float a[4], b[4];
#pragma unroll
      for (int i = 0; i < 4; ++i) a[i] = As[k][tm * 4 + i];
#pragma unroll
      for (int j = 0; j < 4; ++j) b[j] = Bs[k][tn * 4 + j];
#pragma unroll
      for (int i = 0; i < 4; ++i)
#pragma unroll
        for (int j = 0; j < 4; ++j)
          acc[i][j] = fmaf(a[i], b[j], acc[i][j]);
    }
    __syncthreads();
  }
#pragma unroll
  for (int i = 0; i < 4; ++i) {
    int m = m0 + tm * 4 + i;
#pragma unroll
    for (int j = 0; j < 4; ++j) {
      int n = n0 + tn * 4 + j;
      C[(size_t)m * N + n] = acc[i][j] + bias[n];
    }
  }
}

// ---------------------------------------------------------------------------
// Persistent recurrence, ROUND-7: TWO agents, f16 weights in registers.
//
// Evidence trail: r4 (8 WGs, sentinel-on-data sync) = 3070 cy/step, fabric RT
// + barrier + wave0-reduce dominated. r6 (8x8 all-to-all ring) REGRESSED to
// 62 ms with FETCH_SIZE 4.46 GB -> agent-scope atomics are fabric-serviced;
// sync cost scales with polled-lines x agents. So: minimize agents (2) and
// polled bytes (1 KB/step each way).
//
// Decomposition: WG g owns rows [256g, 256g+256). Thread t: r = t&255,
// kh = t>>8 (k-half). Weights Wh[256g+r][256kh..+256) as 128 half2 VGPRs
// (f16 conversion chain is not rematerializable, unlike r1-r3's raw loads).
// Per step s (h_s = tanh(P[s-1] + Wh h_{s-1})):
//   barrier1
//   local waves (kh==g):   dot over OWN half of h (in LDS since last step),
//                          partial[r] -> LDS.   [off remote-critical path]
//   remote waves (kh!=g):  poll peer's 256 floats of h_{s-1} (sentinel
//                          protocol, 1 float/lane), cvt f16 -> LDS.
//   barrier2
//   remote waves: dot remote half (4 waves, 1/SIMD -> 320 cy issue),
//                 + partial[r] + P, tanh, publish fp32 (atomic, agent) +
//                 f16 -> local LDS half for next step.
// ---------------------------------------------------------------------------
__global__ __launch_bounds__(RTHREADS, 2) void rnn_recur(
    const float* __restrict__ P,     // [SEQ][HSZ]  (Wx@x_t + bh)
    const float* __restrict__ Wh,    // [HSZ][HSZ]
    float* __restrict__ h_hist)      // [SEQ+1][HSZ]; row0=0, rows 1..=SENT
{
  const int g = blockIdx.x;          // 0 or 1
  const int tid = threadIdx.x;
  const int r = tid & 255;           // row within this WG's slice
  const int kh = tid >> 8;           // k-half this thread covers
  const int rglob = (g << 8) + r;    // global row this thread produces
  const int lane = tid & 63;
  const int wave = tid >> 6;
  const bool is_remote = (kh != g);  // covers the PEER's h half

  // ---- weights: Wh[rglob][256*kh .. 256*kh+256) as 128 half2 in VGPRs ----
  half2_t wreg[128];
  {
    const float2* wsrc =
        (const float2*)(Wh + (size_t)rglob * HSZ + (kh << 8));
#pragma unroll
    for (int j = 0; j < 128; ++j) {
      float2 wf = wsrc[j];
      half2_t hv;
      hv.x = (_Float16)wf.x;
      hv.y = (_Float16)wf.y;
      unsigned u = __builtin_bit_cast(unsigned, hv);
      asm("" : "+v"(u));             // pin: cvt result can't be remat'd cheaply
      wreg[j] = bch2(u);
    }
  }

  __shared__ __align__(16) _Float16 hbuf[HSZ];  // h_{s-1} as f16 (k-indexed)
  __shared__ float part[256];                   // local-half partials

  // Prologue: h_0 = 0 — final-owner (remote) threads zero the LOCAL f16 half.
  if (is_remote) hbuf[rglob] = (_Float16)0.f;
  // (remote half of hbuf is written by pollers each step, incl. s=1 from
  //  h_hist row 0 which is zero-filled, not sentinel.)

  const uint4* const hb_mine = (const uint4*)(hbuf + (kh << 8)); // wave's half

  for (int s = 1; s <= SEQ; ++s) {
    __syncthreads();   // barrier1: prev step's hbuf writes visible

    if (!is_remote) {
      // Local-half dot: h half is this WG's own, already in LDS.
      float a0 = 0.f, a1 = 0.f, a2 = 0.f, a3 = 0.f;
#pragma unroll
      for (int j = 0; j < 32; ++j) {
        uint4 hv = hb_mine[j];       // broadcast read (all lanes same addr)
        a0 = dot2f(wreg[4 * j + 0], bch2(hv.x), a0);
        a1 = dot2f(wreg[4 * j + 1], bch2(hv.y), a1);
        a2 = dot2f(wreg[4 * j + 2], bch2(hv.z), a2);
        a3 = dot2f(wreg[4 * j + 3], bch2(hv.w), a3);
      }
      part[r] = (a0 + a1) + (a2 + a3);
    } else {
      // Poll the peer's h_{s-1} chunk: wave rw covers remote rows rw*64..+64.
      const int rw = wave & 3;
      const float* hp = h_hist + (size_t)(s - 1) * HSZ + ((1 - g) << 8) +
                        (rw << 6) + lane;
      float vh;
      do {
        vh = __hip_atomic_load(hp, __ATOMIC_RELAXED, __HIP_MEMORY_SCOPE_AGENT);
      } while (__any((int)(__float_as_uint(vh) == SENT)));
      hbuf[((1 - g) << 8) + (rw << 6) + lane] = (_Float16)vh;
    }

    // P[s-1] for the final sum (remote threads own the output row). Issued
    // here so its latency overlaps the barrier.
    float pv = 0.f;
    if (is_remote) pv = P[(size_t)(s - 1) * HSZ + rglob];

    __syncthreads();   // barrier2: remote hbuf half + partials visible

    if (is_remote) {
      float a0 = 0.f, a1 = 0.f, a2 = 0.f, a3 = 0.f;
#pragma unroll
      for (int j = 0; j < 32; ++j) {
        uint4 hv = hb_mine[j];
        a0 = dot2f(wreg[4 * j + 0], bch2(hv.x), a0);
        a1 = dot2f(wreg[4 * j + 1], bch2(hv.y), a1);
        a2 = dot2f(wreg[4 * j + 2], bch2(hv.z), a2);
        a3 = dot2f(wreg[4 * j + 3], bch2(hv.w), a3);
      }
      float xv = ((a0 + a1) + (a2 + a3)) + part[r] + pv;
      xv = fminf(fmaxf(xv, -15.f), 15.f);
      float e = __expf(2.f * xv);
      float hn = 1.f - 2.f / (e + 1.f);
      // Publish fp32 (the value IS the ready signal — r4-proven protocol)...
      __hip_atomic_store(&h_hist[(size_t)s * HSZ + rglob], hn,
                         __ATOMIC_RELAXED, __HIP_MEMORY_SCOPE_AGENT);
      // ...and stage f16 locally for the next step's local-half dot.
      hbuf[rglob] = (_Float16)hn;
    }
  }
}

// ---------------------------------------------------------------------------
extern "C" void kernel_launch(void* const* d_in, const int* in_sizes, int n_in,
                              void* d_out, int out_size, void* d_ws, size_t ws_size,
                              hipStream_t stream) {
  const float* x  = (const float*)d_in[0];  // [SEQ][ISZ]
  const float* Wx = (const float*)d_in[1];  // [HSZ][ISZ]
  const float* Wh = (const float*)d_in[2];  // [HSZ][HSZ]
  const float* Wy = (const float*)d_in[3];  // [OSZ][HSZ]
  const float* bh = (const float*)d_in[4];  // [HSZ]
  const float* by = (const float*)d_in[5];  // [OSZ]
  float* out = (float*)d_out;               // [SEQ][OSZ]

  float* P      = (float*)d_ws;             // SEQ*HSZ      (64 MB)
  float* h_hist = P + (size_t)SEQ * HSZ;    // (SEQ+1)*HSZ  (64 MB)

  // Sentinel-fill h_hist rows (NaN bits), then zero row 0 (= h_0).
  hipMemsetD32Async((hipDeviceptr_t)h_hist, (int)SENT,
                    (size_t)(SEQ + 1) * HSZ, stream);
  hipMemsetAsync(h_hist, 0, HSZ * sizeof(float), stream);

  // Phase 1: P = x @ Wx^T + bh
  gemm_bt_bias<<<dim3(SEQ / 64, HSZ / 64), dim3(256), 0, stream>>>(
      x, Wx, bh, P, SEQ, HSZ, ISZ);

  // Phase 2: sequential recurrence (2 persistent WGs, f16 weights in regs)
  rnn_recur<<<dim3(GWG), dim3(RTHREADS), 0, stream>>>(P, Wh, h_hist);

  // Phase 3: y = h_hist[1..] @ Wy^T + by
  gemm_bt_bias<<<dim3(SEQ / 64, OSZ / 64), dim3(256), 0, stream>>>(
      h_hist + HSZ, Wy, by, out, SEQ, OSZ, HSZ);
}